// Round 1
// baseline (5895.390 us; speedup 1.0000x reference)
//
#include <hip/hip_runtime.h>
#include <cstddef>
#include <cstdint>

#define NROWS 8192
#define DIM   768
#define HID1  512
#define HID2  256

__device__ __forceinline__ float geluf(float x) {
    return 0.5f * x * (1.0f + erff(x * 0.70710678118654752f));
}
__device__ __forceinline__ float softplusf(float x) {
    return fmaxf(x, 0.0f) + log1pf(expf(-fabsf(x)));
}
__device__ __forceinline__ float sigm(float x) {
    return 1.0f / (1.0f + expf(-x));
}

// ---------------- zero fill ----------------
__global__ void zero_u32(unsigned* __restrict__ p, int n) {
    int i = blockIdx.x * blockDim.x + threadIdx.x;
    int stride = gridDim.x * blockDim.x;
    for (; i < n; i += stride) p[i] = 0u;
}

// ---------------- generic tiled f32 GEMM ----------------
// C[M,Nc] = epi(A[M,K] @ B[K,Nc] + bias); EPI: 0 none, 1 gelu(x+bias), 2 gelu(x+bias)+R
template<int EPI>
__global__ __launch_bounds__(256) void gemm_f32(
    const float* __restrict__ A, const float* __restrict__ B,
    const float* __restrict__ bias, const float* __restrict__ R,
    float* __restrict__ C, int M, int Nc, int K)
{
    __shared__ float As[64][20];
    __shared__ float Bs[16][68];
    const int tid = threadIdx.x;
    const int tx = tid & 15, ty = tid >> 4;
    const int m0 = blockIdx.x * 64, n0 = blockIdx.y * 64;
    const int lr = tid >> 2, lq = tid & 3;
    float acc[4][4] = {};
    for (int k0 = 0; k0 < K; k0 += 16) {
        float4 av = *(const float4*)(A + (size_t)(m0 + lr) * K + k0 + lq * 4);
        float4 bv = *(const float4*)(B + (size_t)(k0 + ty) * Nc + n0 + tx * 4);
        *(float4*)&As[lr][lq * 4] = av;
        *(float4*)&Bs[ty][tx * 4] = bv;
        __syncthreads();
        #pragma unroll
        for (int kk = 0; kk < 16; ++kk) {
            float a_[4], b_[4];
            *(float4*)b_ = *(const float4*)&Bs[kk][tx * 4];
            a_[0] = As[ty*4+0][kk]; a_[1] = As[ty*4+1][kk];
            a_[2] = As[ty*4+2][kk]; a_[3] = As[ty*4+3][kk];
            #pragma unroll
            for (int ii = 0; ii < 4; ++ii)
                #pragma unroll
                for (int jj = 0; jj < 4; ++jj)
                    acc[ii][jj] = fmaf(a_[ii], b_[jj], acc[ii][jj]);
        }
        __syncthreads();
    }
    #pragma unroll
    for (int ii = 0; ii < 4; ++ii) {
        const int row = m0 + ty * 4 + ii;
        #pragma unroll
        for (int jj = 0; jj < 4; ++jj) {
            const int col = n0 + tx * 4 + jj;
            float v = acc[ii][jj];
            if (EPI >= 1) v = geluf(v + bias[col]);
            if (EPI == 2) v += R[(size_t)row * Nc + col];
            C[(size_t)row * Nc + col] = v;
        }
    }
}

// ---------------- streaming S-GEMM + per-row top-5 ----------------
// Ab[i,j] = al*A[i,j] + (1-al)*relu(Y[i]·X[j]); per (row, colsplit) write top-5 (val,idx).
__global__ __launch_bounds__(256) void stopk(
    const float* __restrict__ Y, const float* __restrict__ X,
    const float* __restrict__ Aad, const float* __restrict__ ra_p,
    float* __restrict__ PARTV, int* __restrict__ PARTI)
{
    __shared__ float Ys[64][20];
    __shared__ float Xs[64][20];
    __shared__ float cv[64][81];
    __shared__ int   ci[64][81];
    const int tid = threadIdx.x;
    const int tx = tid & 15, ty = tid >> 4;
    const int row0 = blockIdx.x * 64;
    const int cs = blockIdx.y;
    const float al = sigm(ra_p[0]);
    const float oma = 1.0f - al;
    const int lr = tid >> 2, lq = tid & 3;

    float t5v[4][5];
    int   t5i[4][5];
    #pragma unroll
    for (int ii = 0; ii < 4; ++ii)
        #pragma unroll
        for (int s = 0; s < 5; ++s) { t5v[ii][s] = -1.0f; t5i[ii][s] = 0x7fffffff; }

    for (int ct = 0; ct < 16; ++ct) {
        const int col0 = cs * 1024 + ct * 64;
        float acc[4][4] = {};
        for (int k0 = 0; k0 < DIM; k0 += 16) {
            float4 yv = *(const float4*)(Y + (size_t)(row0 + lr) * DIM + k0 + lq * 4);
            float4 xv = *(const float4*)(X + (size_t)(col0 + lr) * DIM + k0 + lq * 4);
            *(float4*)&Ys[lr][lq * 4] = yv;
            *(float4*)&Xs[lr][lq * 4] = xv;
            __syncthreads();
            #pragma unroll
            for (int kk = 0; kk < 16; ++kk) {
                float a_[4], b_[4];
                a_[0] = Ys[ty*4+0][kk]; a_[1] = Ys[ty*4+1][kk];
                a_[2] = Ys[ty*4+2][kk]; a_[3] = Ys[ty*4+3][kk];
                b_[0] = Xs[tx*4+0][kk]; b_[1] = Xs[tx*4+1][kk];
                b_[2] = Xs[tx*4+2][kk]; b_[3] = Xs[tx*4+3][kk];
                #pragma unroll
                for (int ii = 0; ii < 4; ++ii)
                    #pragma unroll
                    for (int jj = 0; jj < 4; ++jj)
                        acc[ii][jj] = fmaf(a_[ii], b_[jj], acc[ii][jj]);
            }
            __syncthreads();
        }
        // epilogue: combine with A, update per-thread top-5 (cols ascending -> strict > keeps lowest index on ties)
        #pragma unroll
        for (int ii = 0; ii < 4; ++ii) {
            const int row = row0 + ty * 4 + ii;
            const float* arow = Aad + (size_t)row * NROWS + col0 + tx * 4;
            #pragma unroll
            for (int jj = 0; jj < 4; ++jj) {
                const float ab = al * arow[jj] + oma * fmaxf(acc[ii][jj], 0.0f);
                const int col = col0 + tx * 4 + jj;
                if (ab > t5v[ii][4]) {
                    t5v[ii][4] = ab; t5i[ii][4] = col;
                    #pragma unroll
                    for (int s = 4; s > 0; --s) {
                        if (t5v[ii][s] > t5v[ii][s-1]) {
                            float tv = t5v[ii][s]; t5v[ii][s] = t5v[ii][s-1]; t5v[ii][s-1] = tv;
                            int   ti = t5i[ii][s]; t5i[ii][s] = t5i[ii][s-1]; t5i[ii][s-1] = ti;
                        }
                    }
                }
            }
        }
    }
    // merge 16 per-row lists within the block
    #pragma unroll
    for (int ii = 0; ii < 4; ++ii) {
        const int r = ty * 4 + ii;
        #pragma unroll
        for (int s = 0; s < 5; ++s) { cv[r][tx * 5 + s] = t5v[ii][s]; ci[r][tx * 5 + s] = t5i[ii][s]; }
    }
    __syncthreads();
    if (tid < 64) {
        const int r = tid;
        for (int s = 0; s < 5; ++s) {
            float bv = -2.0f; int bi = 0x7fffffff; int bq = 0;
            for (int q = 0; q < 80; ++q) {
                const float v = cv[r][q]; const int ix = ci[r][q];
                if (v > bv || (v == bv && ix < bi)) { bv = v; bi = ix; bq = q; }
            }
            cv[r][bq] = -3.0f;   // LDS: runtime index OK
            PARTV[(size_t)(row0 + r) * 40 + cs * 5 + s] = bv;
            PARTI[(size_t)(row0 + r) * 40 + cs * 5 + s] = bi;
        }
    }
}

// ---------------- merge 8 column-split top-5 lists -> final top-5 indices ----------------
__global__ void topk_merge(const float* __restrict__ PARTV, const int* __restrict__ PARTI,
                           int* __restrict__ TOPK)
{
    const int r = blockIdx.x * blockDim.x + threadIdx.x;
    if (r >= NROWS) return;
    float v[40]; int ix[40];
    #pragma unroll
    for (int q = 0; q < 40; ++q) { v[q] = PARTV[(size_t)r * 40 + q]; ix[q] = PARTI[(size_t)r * 40 + q]; }
    // selection without mutation (keeps arrays register-resident): lexicographic (v desc, idx asc)
    float pv = 3.4e38f; int pi = -1;
    for (int s = 0; s < 5; ++s) {
        float bv = -2.0f; int bi = 0x7fffffff;
        #pragma unroll
        for (int q = 0; q < 40; ++q) {
            const bool lt_prev = (v[q] < pv) || (v[q] == pv && ix[q] > pi);
            const bool gt_best = (v[q] > bv) || (v[q] == bv && ix[q] < bi);
            if (lt_prev && gt_best) { bv = v[q]; bi = ix[q]; }
        }
        TOPK[r * 5 + s] = bi;
        pv = bv; pi = bi;
    }
}

// ---------------- build symmetric adjacency bitmask ----------------
__global__ void bits_set(const int* __restrict__ TOPK, unsigned* __restrict__ BITS)
{
    const int r = blockIdx.x * blockDim.x + threadIdx.x;
    if (r >= NROWS) return;
    #pragma unroll
    for (int t = 0; t < 5; ++t) {
        const int j = TOPK[r * 5 + t];
        if (j != r) {
            atomicOr(&BITS[(size_t)r * 256 + (j >> 5)], 1u << (j & 31));
            atomicOr(&BITS[(size_t)j * 256 + (r >> 5)], 1u << (r & 31));
        }
    }
}

// ---------------- wave-per-row normalized SpMM ----------------
// MF[i,:] = (1/max(rowsum,1e-8)) * sum_{j in mask(i), j!=i} Ab[i,j] * G[j] * X[j,:]
__global__ __launch_bounds__(64) void spmm_row(
    const unsigned* __restrict__ BITS, const float* __restrict__ Y, const float* __restrict__ X,
    const float* __restrict__ Aad, const float* __restrict__ G, const float* __restrict__ ra_p,
    float* __restrict__ MF)
{
    const int i = blockIdx.x;
    const int t = threadIdx.x;
    const float al = sigm(ra_p[0]);
    const float oma = 1.0f - al;
    float Yl[12];
    #pragma unroll
    for (int e = 0; e < 12; ++e) Yl[e] = Y[(size_t)i * DIM + e * 64 + t];
    float accO[12] = {};
    float rowsum = 0.0f;
    const unsigned* brow = BITS + (size_t)i * 256;
    for (int w = 0; w < 256; ++w) {
        unsigned word = brow[w];
        while (word) {
            const int b = __ffs(word) - 1;
            word &= word - 1;
            const int j = w * 32 + b;
            float Xr[12];
            float part = 0.0f;
            #pragma unroll
            for (int e = 0; e < 12; ++e) {
                Xr[e] = X[(size_t)j * DIM + e * 64 + t];
                part = fmaf(Yl[e], Xr[e], part);
            }
            #pragma unroll
            for (int off = 32; off; off >>= 1) part += __shfl_xor(part, off);
            const float ab = al * Aad[(size_t)i * NROWS + j] + oma * fmaxf(part, 0.0f);
            const float wgt = ab * G[j];
            #pragma unroll
            for (int e = 0; e < 12; ++e) accO[e] = fmaf(wgt, Xr[e], accO[e]);
            rowsum += ab;
        }
    }
    const float dinv = 1.0f / fmaxf(rowsum, 1e-8f);
    #pragma unroll
    for (int e = 0; e < 12; ++e) MF[(size_t)i * DIM + e * 64 + t] = accO[e] * dinv;
}

// ---------------- NIG head final layer (wave per row) ----------------
template<bool FIRST>
__global__ __launch_bounds__(256) void head_final(
    const float* __restrict__ H2buf, const float* __restrict__ wh, const float* __restrict__ bh,
    const float* __restrict__ gam_p, float* __restrict__ out, float* __restrict__ G)
{
    const int wid = (blockIdx.x * 256 + threadIdx.x) >> 6;
    const int lane = threadIdx.x & 63;
    if (wid >= NROWS) return;
    const float* h = H2buf + (size_t)wid * HID2;
    float a0 = 0, a1 = 0, a2 = 0, a3 = 0;
    for (int k = lane; k < HID2; k += 64) {
        const float hv = h[k];
        const float4 w = *(const float4*)(wh + k * 4);
        a0 = fmaf(hv, w.x, a0); a1 = fmaf(hv, w.y, a1);
        a2 = fmaf(hv, w.z, a2); a3 = fmaf(hv, w.w, a3);
    }
    #pragma unroll
    for (int off = 32; off; off >>= 1) {
        a0 += __shfl_xor(a0, off); a1 += __shfl_xor(a1, off);
        a2 += __shfl_xor(a2, off); a3 += __shfl_xor(a3, off);
    }
    if (lane == 0) {
        const float r0 = a0 + bh[0], r1 = a1 + bh[1], r2 = a2 + bh[2], r3 = a3 + bh[3];
        const float vv = softplusf(r1) + 1e-6f;
        const float aa = softplusf(r2) + 1.0f + 1e-6f;
        const float bb = softplusf(r3) + 1e-6f;
        const int base = FIRST ? 0 : 4 * NROWS;
        out[base + wid]             = r0;
        out[base + NROWS + wid]     = vv;
        out[base + 2 * NROWS + wid] = aa;
        out[base + 3 * NROWS + wid] = bb;
        if (FIRST) {
            const float u0 = bb / fmaxf(aa - 1.0f, 1e-8f);
            G[wid] = 1.0f - gam_p[0] * sigm(u0);
        }
    }
}

extern "C" void kernel_launch(void* const* d_in, const int* in_sizes, int n_in,
                              void* d_out, int out_size, void* d_ws, size_t ws_size,
                              hipStream_t stream) {
    const float* X     = (const float*)d_in[0];
    const float* Aad   = (const float*)d_in[1];
    const float* W_gm  = (const float*)d_in[2];
    const float* ra    = (const float*)d_in[3];
    const float* gam   = (const float*)d_in[4];
    const float* ih_w1 = (const float*)d_in[5];
    const float* ih_b1 = (const float*)d_in[6];
    const float* ih_w2 = (const float*)d_in[7];
    const float* ih_b2 = (const float*)d_in[8];
    const float* ih_wh = (const float*)d_in[9];
    const float* ih_bh = (const float*)d_in[10];
    const float* gcn_w = (const float*)d_in[11];
    const float* gcn_b = (const float*)d_in[12];
    const float* fh_w1 = (const float*)d_in[13];
    const float* fh_b1 = (const float*)d_in[14];
    const float* fh_w2 = (const float*)d_in[15];
    const float* fh_b2 = (const float*)d_in[16];
    const float* fh_wh = (const float*)d_in[17];
    const float* fh_bh = (const float*)d_in[18];
    float* out = (float*)d_out;

    char* ws = (char*)d_ws;
    size_t off = 0;
    float* Y    = (float*)(ws + off); off += (size_t)NROWS * DIM * 4;   // 25.2 MB (aliased as X2 later)
    float* MF   = (float*)(ws + off); off += (size_t)NROWS * DIM * 4;   // 25.2 MB
    float* H1b  = (float*)(ws + off); off += (size_t)NROWS * HID1 * 4;  // 16.8 MB
    float* H2b  = (float*)(ws + off); off += (size_t)NROWS * HID2 * 4;  // 8.4 MB
    float* Gv   = (float*)(ws + off); off += (size_t)NROWS * 4;
    unsigned* BITS = (unsigned*)(ws + off); off += (size_t)NROWS * 256 * 4; // 8.4 MB
    float* PARTV = (float*)(ws + off); off += (size_t)NROWS * 40 * 4;
    int*   PARTI = (int*)(ws + off);   off += (size_t)NROWS * 40 * 4;
    int*   TOPK  = (int*)(ws + off);   off += (size_t)NROWS * 5 * 4;
    float* X2 = Y;  // Y dead after spmm_row; X2 born after

    // clear adjacency bitmask
    zero_u32<<<2048, 256, 0, stream>>>(BITS, NROWS * 256);

    // Y = X @ W_gm
    gemm_f32<0><<<dim3(NROWS / 64, DIM / 64), 256, 0, stream>>>(X, W_gm, nullptr, nullptr, Y, NROWS, DIM, DIM);
    // head 1 MLP
    gemm_f32<1><<<dim3(NROWS / 64, HID1 / 64), 256, 0, stream>>>(X, ih_w1, ih_b1, nullptr, H1b, NROWS, HID1, DIM);
    gemm_f32<1><<<dim3(NROWS / 64, HID2 / 64), 256, 0, stream>>>(H1b, ih_w2, ih_b2, nullptr, H2b, NROWS, HID2, HID1);
    head_final<true><<<NROWS / 4, 256, 0, stream>>>(H2b, ih_wh, ih_bh, gam, out, Gv);

    // streaming S + top-5
    stopk<<<dim3(NROWS / 64, 8), 256, 0, stream>>>(Y, X, Aad, ra, PARTV, PARTI);
    topk_merge<<<NROWS / 256, 256, 0, stream>>>(PARTV, PARTI, TOPK);
    bits_set<<<NROWS / 256, 256, 0, stream>>>(TOPK, BITS);

    // normalized SpMM with on-the-fly Ab recompute and G scaling
    spmm_row<<<NROWS, 64, 0, stream>>>(BITS, Y, X, Aad, Gv, ra, MF);

    // X2 = X + gelu(MF @ gcn_w + gcn_b)
    gemm_f32<2><<<dim3(NROWS / 64, DIM / 64), 256, 0, stream>>>(MF, gcn_w, gcn_b, X, X2, NROWS, DIM, DIM);

    // head 2 MLP
    gemm_f32<1><<<dim3(NROWS / 64, HID1 / 64), 256, 0, stream>>>(X2, fh_w1, fh_b1, nullptr, H1b, NROWS, HID1, DIM);
    gemm_f32<1><<<dim3(NROWS / 64, HID2 / 64), 256, 0, stream>>>(H1b, fh_w2, fh_b2, nullptr, H2b, NROWS, HID2, HID1);
    head_final<false><<<NROWS / 4, 256, 0, stream>>>(H2b, fh_wh, fh_bh, gam, out, Gv);
}

// Round 2
// 2889.322 us; speedup vs baseline: 2.0404x; 2.0404x over previous
//
#include <hip/hip_runtime.h>
#include <cstddef>
#include <cstdint>

#define NROWS 8192
#define DIM   768
#define HID1  512
#define HID2  256

__device__ __forceinline__ float geluf(float x) {
    return 0.5f * x * (1.0f + erff(x * 0.70710678118654752f));
}
__device__ __forceinline__ float softplusf(float x) {
    return fmaxf(x, 0.0f) + log1pf(expf(-fabsf(x)));
}
__device__ __forceinline__ float sigm(float x) {
    return 1.0f / (1.0f + expf(-x));
}

// ---------------- zero fill ----------------
__global__ void zero_u32(unsigned* __restrict__ p, int n) {
    int i = blockIdx.x * blockDim.x + threadIdx.x;
    int stride = gridDim.x * blockDim.x;
    for (; i < n; i += stride) p[i] = 0u;
}

// ---------------- generic tiled f32 GEMM (k-major LDS, conflict-free b128 reads) ----------------
// C[M,Nc] = epi(A[M,K] @ B[K,Nc] + bias); EPI: 0 none, 1 gelu(x+bias), 2 gelu(x+bias)+R
template<int EPI>
__global__ __launch_bounds__(256) void gemm_f32(
    const float* __restrict__ A, const float* __restrict__ B,
    const float* __restrict__ bias, const float* __restrict__ R,
    float* __restrict__ C, int M, int Nc, int K)
{
    __shared__ float AsT[16][68];   // k-major: AsT[k][m]
    __shared__ float Bs[16][68];    // k-major already: Bs[k][n]
    const int tid = threadIdx.x;
    const int tx = tid & 15, ty = tid >> 4;
    const int m0 = blockIdx.x * 64, n0 = blockIdx.y * 64;
    const int lr = tid >> 2, lq = tid & 3;
    float acc[4][4] = {};
    for (int k0 = 0; k0 < K; k0 += 16) {
        float4 av = *(const float4*)(A + (size_t)(m0 + lr) * K + k0 + lq * 4);
        float4 bv = *(const float4*)(B + (size_t)(k0 + ty) * Nc + n0 + tx * 4);
        // transpose-on-store: lanes with equal lq write consecutive lr -> 2-way max (free)
        AsT[lq * 4 + 0][lr] = av.x;
        AsT[lq * 4 + 1][lr] = av.y;
        AsT[lq * 4 + 2][lr] = av.z;
        AsT[lq * 4 + 3][lr] = av.w;
        *(float4*)&Bs[ty][tx * 4] = bv;
        __syncthreads();
        #pragma unroll
        for (int kk = 0; kk < 16; ++kk) {
            float4 a4 = *(const float4*)&AsT[kk][ty * 4];   // 16-lane broadcast
            float4 b4 = *(const float4*)&Bs[kk][tx * 4];    // 2 lanes/bank
            const float a_[4] = {a4.x, a4.y, a4.z, a4.w};
            const float b_[4] = {b4.x, b4.y, b4.z, b4.w};
            #pragma unroll
            for (int ii = 0; ii < 4; ++ii)
                #pragma unroll
                for (int jj = 0; jj < 4; ++jj)
                    acc[ii][jj] = fmaf(a_[ii], b_[jj], acc[ii][jj]);
        }
        __syncthreads();
    }
    #pragma unroll
    for (int ii = 0; ii < 4; ++ii) {
        const int row = m0 + ty * 4 + ii;
        #pragma unroll
        for (int jj = 0; jj < 4; ++jj) {
            const int col = n0 + tx * 4 + jj;
            float v = acc[ii][jj];
            if (EPI >= 1) v = geluf(v + bias[col]);
            if (EPI == 2) v += R[(size_t)row * Nc + col];
            C[(size_t)row * Nc + col] = v;
        }
    }
}

// ---------------- streaming S-GEMM + per-row top-5 ----------------
// Ab[i,j] = al*A[i,j] + (1-al)*relu(Y[i]·X[j]); per (row, colsplit) write top-5 (val,idx).
// LDS: tiles (k-major, 8.5KB) aliased with merge arrays (31.1KB) -> 31.1KB total.
__global__ __launch_bounds__(256) void stopk(
    const float* __restrict__ Y, const float* __restrict__ X,
    const float* __restrict__ Aad, const float* __restrict__ ra_p,
    float* __restrict__ PARTV, int* __restrict__ PARTI)
{
    __shared__ __align__(16) char smem[64 * 81 * 4 + 64 * 81 * 2 + 16];
    float (*YsT)[68] = (float(*)[68])smem;                       // [16][68]
    float (*XsT)[68] = (float(*)[68])(smem + 16 * 68 * 4);       // [16][68]
    float (*cv)[81]  = (float(*)[81])smem;                       // [64][81] (aliases tiles; used after)
    unsigned short (*ci)[81] = (unsigned short(*)[81])(smem + 64 * 81 * 4);

    const int tid = threadIdx.x;
    const int tx = tid & 15, ty = tid >> 4;
    const int row0 = blockIdx.x * 64;
    const int cs = blockIdx.y;
    const float al = sigm(ra_p[0]);
    const float oma = 1.0f - al;
    const int lr = tid >> 2, lq = tid & 3;

    float t5v[4][5];
    int   t5i[4][5];
    #pragma unroll
    for (int ii = 0; ii < 4; ++ii)
        #pragma unroll
        for (int s = 0; s < 5; ++s) { t5v[ii][s] = -1.0f; t5i[ii][s] = 0x7fffffff; }

    for (int ct = 0; ct < 16; ++ct) {
        const int col0 = cs * 1024 + ct * 64;
        float acc[4][4] = {};
        for (int k0 = 0; k0 < DIM; k0 += 16) {
            float4 yv = *(const float4*)(Y + (size_t)(row0 + lr) * DIM + k0 + lq * 4);
            float4 xv = *(const float4*)(X + (size_t)(col0 + lr) * DIM + k0 + lq * 4);
            YsT[lq * 4 + 0][lr] = yv.x;
            YsT[lq * 4 + 1][lr] = yv.y;
            YsT[lq * 4 + 2][lr] = yv.z;
            YsT[lq * 4 + 3][lr] = yv.w;
            XsT[lq * 4 + 0][lr] = xv.x;
            XsT[lq * 4 + 1][lr] = xv.y;
            XsT[lq * 4 + 2][lr] = xv.z;
            XsT[lq * 4 + 3][lr] = xv.w;
            __syncthreads();
            #pragma unroll
            for (int kk = 0; kk < 16; ++kk) {
                float4 a4 = *(const float4*)&YsT[kk][ty * 4];   // broadcast
                float4 b4 = *(const float4*)&XsT[kk][tx * 4];   // 2 lanes/bank
                const float a_[4] = {a4.x, a4.y, a4.z, a4.w};
                const float b_[4] = {b4.x, b4.y, b4.z, b4.w};
                #pragma unroll
                for (int ii = 0; ii < 4; ++ii)
                    #pragma unroll
                    for (int jj = 0; jj < 4; ++jj)
                        acc[ii][jj] = fmaf(a_[ii], b_[jj], acc[ii][jj]);
            }
            __syncthreads();
        }
        // epilogue: combine with A, update per-thread top-5 (cols ascending -> strict > keeps lowest index on ties)
        #pragma unroll
        for (int ii = 0; ii < 4; ++ii) {
            const int row = row0 + ty * 4 + ii;
            const float* arow = Aad + (size_t)row * NROWS + col0 + tx * 4;
            #pragma unroll
            for (int jj = 0; jj < 4; ++jj) {
                const float ab = al * arow[jj] + oma * fmaxf(acc[ii][jj], 0.0f);
                const int col = col0 + tx * 4 + jj;
                if (ab > t5v[ii][4]) {
                    t5v[ii][4] = ab; t5i[ii][4] = col;
                    #pragma unroll
                    for (int s = 4; s > 0; --s) {
                        if (t5v[ii][s] > t5v[ii][s-1]) {
                            float tv = t5v[ii][s]; t5v[ii][s] = t5v[ii][s-1]; t5v[ii][s-1] = tv;
                            int   ti = t5i[ii][s]; t5i[ii][s] = t5i[ii][s-1]; t5i[ii][s-1] = ti;
                        }
                    }
                }
            }
        }
    }
    // merge 16 per-row lists within the block (cv/ci alias tile LDS; tiles dead past last sync)
    #pragma unroll
    for (int ii = 0; ii < 4; ++ii) {
        const int r = ty * 4 + ii;
        #pragma unroll
        for (int s = 0; s < 5; ++s) {
            cv[r][tx * 5 + s] = t5v[ii][s];
            ci[r][tx * 5 + s] = (unsigned short)t5i[ii][s];
        }
    }
    __syncthreads();
    if (tid < 64) {
        const int r = tid;
        for (int s = 0; s < 5; ++s) {
            float bv = -2.0f; int bi = 0x7fffffff; int bq = 0;
            for (int q = 0; q < 80; ++q) {
                const float v = cv[r][q]; const int ix = (int)ci[r][q];
                if (v > bv || (v == bv && ix < bi)) { bv = v; bi = ix; bq = q; }
            }
            cv[r][bq] = -3.0f;   // LDS: runtime index OK
            PARTV[(size_t)(row0 + r) * 40 + cs * 5 + s] = bv;
            PARTI[(size_t)(row0 + r) * 40 + cs * 5 + s] = bi;
        }
    }
}

// ---------------- merge 8 column-split top-5 lists -> final top-5 indices ----------------
__global__ void topk_merge(const float* __restrict__ PARTV, const int* __restrict__ PARTI,
                           int* __restrict__ TOPK)
{
    const int r = blockIdx.x * blockDim.x + threadIdx.x;
    if (r >= NROWS) return;
    float v[40]; int ix[40];
    #pragma unroll
    for (int q = 0; q < 40; ++q) { v[q] = PARTV[(size_t)r * 40 + q]; ix[q] = PARTI[(size_t)r * 40 + q]; }
    // selection without mutation (keeps arrays register-resident): lexicographic (v desc, idx asc)
    float pv = 3.4e38f; int pi = -1;
    for (int s = 0; s < 5; ++s) {
        float bv = -2.0f; int bi = 0x7fffffff;
        #pragma unroll
        for (int q = 0; q < 40; ++q) {
            const bool lt_prev = (v[q] < pv) || (v[q] == pv && ix[q] > pi);
            const bool gt_best = (v[q] > bv) || (v[q] == bv && ix[q] < bi);
            if (lt_prev && gt_best) { bv = v[q]; bi = ix[q]; }
        }
        TOPK[r * 5 + s] = bi;
        pv = bv; pi = bi;
    }
}

// ---------------- build symmetric adjacency bitmask ----------------
__global__ void bits_set(const int* __restrict__ TOPK, unsigned* __restrict__ BITS)
{
    const int r = blockIdx.x * blockDim.x + threadIdx.x;
    if (r >= NROWS) return;
    #pragma unroll
    for (int t = 0; t < 5; ++t) {
        const int j = TOPK[r * 5 + t];
        if (j != r) {
            atomicOr(&BITS[(size_t)r * 256 + (j >> 5)], 1u << (j & 31));
            atomicOr(&BITS[(size_t)j * 256 + (r >> 5)], 1u << (r & 31));
        }
    }
}

// ---------------- wave-per-row normalized SpMM ----------------
// MF[i,:] = (1/max(rowsum,1e-8)) * sum_{j in mask(i), j!=i} Ab[i,j] * G[j] * X[j,:]
__global__ __launch_bounds__(64) void spmm_row(
    const unsigned* __restrict__ BITS, const float* __restrict__ Y, const float* __restrict__ X,
    const float* __restrict__ Aad, const float* __restrict__ G, const float* __restrict__ ra_p,
    float* __restrict__ MF)
{
    const int i = blockIdx.x;
    const int t = threadIdx.x;
    const float al = sigm(ra_p[0]);
    const float oma = 1.0f - al;
    float Yl[12];
    #pragma unroll
    for (int e = 0; e < 12; ++e) Yl[e] = Y[(size_t)i * DIM + e * 64 + t];
    float accO[12] = {};
    float rowsum = 0.0f;
    const unsigned* brow = BITS + (size_t)i * 256;
    for (int w = 0; w < 256; ++w) {
        unsigned word = brow[w];
        while (word) {
            const int b = __ffs(word) - 1;
            word &= word - 1;
            const int j = w * 32 + b;
            float Xr[12];
            float part = 0.0f;
            #pragma unroll
            for (int e = 0; e < 12; ++e) {
                Xr[e] = X[(size_t)j * DIM + e * 64 + t];
                part = fmaf(Yl[e], Xr[e], part);
            }
            #pragma unroll
            for (int off = 32; off; off >>= 1) part += __shfl_xor(part, off);
            const float ab = al * Aad[(size_t)i * NROWS + j] + oma * fmaxf(part, 0.0f);
            const float wgt = ab * G[j];
            #pragma unroll
            for (int e = 0; e < 12; ++e) accO[e] = fmaf(wgt, Xr[e], accO[e]);
            rowsum += ab;
        }
    }
    const float dinv = 1.0f / fmaxf(rowsum, 1e-8f);
    #pragma unroll
    for (int e = 0; e < 12; ++e) MF[(size_t)i * DIM + e * 64 + t] = accO[e] * dinv;
}

// ---------------- NIG head final layer (wave per row) ----------------
template<bool FIRST>
__global__ __launch_bounds__(256) void head_final(
    const float* __restrict__ H2buf, const float* __restrict__ wh, const float* __restrict__ bh,
    const float* __restrict__ gam_p, float* __restrict__ out, float* __restrict__ G)
{
    const int wid = (blockIdx.x * 256 + threadIdx.x) >> 6;
    const int lane = threadIdx.x & 63;
    if (wid >= NROWS) return;
    const float* h = H2buf + (size_t)wid * HID2;
    float a0 = 0, a1 = 0, a2 = 0, a3 = 0;
    for (int k = lane; k < HID2; k += 64) {
        const float hv = h[k];
        const float4 w = *(const float4*)(wh + k * 4);
        a0 = fmaf(hv, w.x, a0); a1 = fmaf(hv, w.y, a1);
        a2 = fmaf(hv, w.z, a2); a3 = fmaf(hv, w.w, a3);
    }
    #pragma unroll
    for (int off = 32; off; off >>= 1) {
        a0 += __shfl_xor(a0, off); a1 += __shfl_xor(a1, off);
        a2 += __shfl_xor(a2, off); a3 += __shfl_xor(a3, off);
    }
    if (lane == 0) {
        const float r0 = a0 + bh[0], r1 = a1 + bh[1], r2 = a2 + bh[2], r3 = a3 + bh[3];
        const float vv = softplusf(r1) + 1e-6f;
        const float aa = softplusf(r2) + 1.0f + 1e-6f;
        const float bb = softplusf(r3) + 1e-6f;
        const int base = FIRST ? 0 : 4 * NROWS;
        out[base + wid]             = r0;
        out[base + NROWS + wid]     = vv;
        out[base + 2 * NROWS + wid] = aa;
        out[base + 3 * NROWS + wid] = bb;
        if (FIRST) {
            const float u0 = bb / fmaxf(aa - 1.0f, 1e-8f);
            G[wid] = 1.0f - gam_p[0] * sigm(u0);
        }
    }
}

extern "C" void kernel_launch(void* const* d_in, const int* in_sizes, int n_in,
                              void* d_out, int out_size, void* d_ws, size_t ws_size,
                              hipStream_t stream) {
    const float* X     = (const float*)d_in[0];
    const float* Aad   = (const float*)d_in[1];
    const float* W_gm  = (const float*)d_in[2];
    const float* ra    = (const float*)d_in[3];
    const float* gam   = (const float*)d_in[4];
    const float* ih_w1 = (const float*)d_in[5];
    const float* ih_b1 = (const float*)d_in[6];
    const float* ih_w2 = (const float*)d_in[7];
    const float* ih_b2 = (const float*)d_in[8];
    const float* ih_wh = (const float*)d_in[9];
    const float* ih_bh = (const float*)d_in[10];
    const float* gcn_w = (const float*)d_in[11];
    const float* gcn_b = (const float*)d_in[12];
    const float* fh_w1 = (const float*)d_in[13];
    const float* fh_b1 = (const float*)d_in[14];
    const float* fh_w2 = (const float*)d_in[15];
    const float* fh_b2 = (const float*)d_in[16];
    const float* fh_wh = (const float*)d_in[17];
    const float* fh_bh = (const float*)d_in[18];
    float* out = (float*)d_out;

    char* ws = (char*)d_ws;
    size_t off = 0;
    float* Y    = (float*)(ws + off); off += (size_t)NROWS * DIM * 4;   // 25.2 MB (aliased as X2 later)
    float* MF   = (float*)(ws + off); off += (size_t)NROWS * DIM * 4;   // 25.2 MB
    float* H1b  = (float*)(ws + off); off += (size_t)NROWS * HID1 * 4;  // 16.8 MB
    float* H2b  = (float*)(ws + off); off += (size_t)NROWS * HID2 * 4;  // 8.4 MB
    float* Gv   = (float*)(ws + off); off += (size_t)NROWS * 4;
    unsigned* BITS = (unsigned*)(ws + off); off += (size_t)NROWS * 256 * 4; // 8.4 MB
    float* PARTV = (float*)(ws + off); off += (size_t)NROWS * 40 * 4;
    int*   PARTI = (int*)(ws + off);   off += (size_t)NROWS * 40 * 4;
    int*   TOPK  = (int*)(ws + off);   off += (size_t)NROWS * 5 * 4;
    float* X2 = Y;  // Y dead after spmm_row; X2 born after

    // clear adjacency bitmask
    zero_u32<<<2048, 256, 0, stream>>>(BITS, NROWS * 256);

    // Y = X @ W_gm
    gemm_f32<0><<<dim3(NROWS / 64, DIM / 64), 256, 0, stream>>>(X, W_gm, nullptr, nullptr, Y, NROWS, DIM, DIM);
    // head 1 MLP
    gemm_f32<1><<<dim3(NROWS / 64, HID1 / 64), 256, 0, stream>>>(X, ih_w1, ih_b1, nullptr, H1b, NROWS, HID1, DIM);
    gemm_f32<1><<<dim3(NROWS / 64, HID2 / 64), 256, 0, stream>>>(H1b, ih_w2, ih_b2, nullptr, H2b, NROWS, HID2, HID1);
    head_final<true><<<NROWS / 4, 256, 0, stream>>>(H2b, ih_wh, ih_bh, gam, out, Gv);

    // streaming S + top-5
    stopk<<<dim3(NROWS / 64, 8), 256, 0, stream>>>(Y, X, Aad, ra, PARTV, PARTI);
    topk_merge<<<NROWS / 256, 256, 0, stream>>>(PARTV, PARTI, TOPK);
    bits_set<<<NROWS / 256, 256, 0, stream>>>(TOPK, BITS);

    // normalized SpMM with on-the-fly Ab recompute and G scaling
    spmm_row<<<NROWS, 64, 0, stream>>>(BITS, Y, X, Aad, Gv, ra, MF);

    // X2 = X + gelu(MF @ gcn_w + gcn_b)
    gemm_f32<2><<<dim3(NROWS / 64, DIM / 64), 256, 0, stream>>>(MF, gcn_w, gcn_b, X, X2, NROWS, DIM, DIM);

    // head 2 MLP
    gemm_f32<1><<<dim3(NROWS / 64, HID1 / 64), 256, 0, stream>>>(X2, fh_w1, fh_b1, nullptr, H1b, NROWS, HID1, DIM);
    gemm_f32<1><<<dim3(NROWS / 64, HID2 / 64), 256, 0, stream>>>(H1b, fh_w2, fh_b2, nullptr, H2b, NROWS, HID2, HID1);
    head_final<false><<<NROWS / 4, 256, 0, stream>>>(H2b, fh_wh, fh_bh, gam, out, Gv);
}